// Round 8
// baseline (299.349 us; speedup 1.0000x reference)
//
#include <hip/hip_runtime.h>
#include <hip/hip_bf16.h>

// Problem: out[b,o] = sum_i inputs[b,i] * mean[indices[i,o]] + bias[o]
// B=2048, IN=4096, OUT=4096.  inputs f32, indices i32, mean f32, bias f32, out f32.

#define M_DIM 2048
#define K_DIM 4096
#define N_DIM 4096

#define BM 128
#define BN 256
#define BK 64
#define NT (K_DIM / BK)             // 64 K-tiles
#define TILE_B (BN * BK * 2)        // 32768 B per LDS tile (B only!)

typedef __attribute__((ext_vector_type(8))) short short8v;
typedef __attribute__((ext_vector_type(4))) float f32x4;

__device__ __forceinline__ unsigned short f2bf(float x) {
    unsigned u = __builtin_bit_cast(unsigned, x);
    u += 0x7fffu + ((u >> 16) & 1u);   // round-to-nearest-even
    return (unsigned short)(u >> 16);
}

__device__ __forceinline__ void gload_lds16(const void* g, void* l) {
    __builtin_amdgcn_global_load_lds(
        (const __attribute__((address_space(1))) void*)(uintptr_t)g,
        (__attribute__((address_space(3))) void*)(uintptr_t)l, 16, 0, 0);
}

// ---------------- Kernel 1: A f32 -> bf16 ----------------
__global__ void convert_a_kernel(const float* __restrict__ A,
                                 unsigned short* __restrict__ Abf) {
    int i = blockIdx.x * blockDim.x + threadIdx.x;
    const float4 v = ((const float4*)A)[i];
    ushort4 o;
    o.x = f2bf(v.x); o.y = f2bf(v.y); o.z = f2bf(v.z); o.w = f2bf(v.w);
    ((ushort4*)Abf)[i] = o;
}

// ------------- Kernel 2: decode + transpose: Wt[n][k] = bf16(mean[indices[k][n]]) -------------
__global__ void decode_transpose_kernel(const int* __restrict__ idx,
                                        const float* __restrict__ mean,
                                        unsigned short* __restrict__ Wt) {
    __shared__ float smean[K_DIM];
    __shared__ unsigned short tile[64][65];
    const int t = threadIdx.x;
    for (int i = t; i < K_DIM; i += 256) smean[i] = mean[i];
    __syncthreads();

    const int k0 = blockIdx.y * 64;
    const int n0 = blockIdx.x * 64;
    const int rb = t >> 4;
    const int cb = (t & 15) * 4;

    #pragma unroll
    for (int i = 0; i < 4; ++i) {
        const int r = rb + i * 16;
        const int4 v = *(const int4*)&idx[(size_t)(k0 + r) * N_DIM + n0 + cb];
        tile[cb + 0][r] = f2bf(smean[v.x]);
        tile[cb + 1][r] = f2bf(smean[v.y]);
        tile[cb + 2][r] = f2bf(smean[v.z]);
        tile[cb + 3][r] = f2bf(smean[v.w]);
    }
    __syncthreads();

    #pragma unroll
    for (int i = 0; i < 4; ++i) {
        const int r = rb + i * 16;
        ushort4 o;
        o.x = tile[r][cb + 0];
        o.y = tile[r][cb + 1];
        o.z = tile[r][cb + 2];
        o.w = tile[r][cb + 3];
        *(ushort4*)&Wt[(size_t)(n0 + r) * K_DIM + k0 + cb] = o;
    }
}

// ---------------- Kernel 3: bf16 GEMM  C = Abf @ Wt^T + bias ----------------
// LDS-traffic-balanced version of the round-6 single-barrier structure.
// Round-6 analysis: LDS pipe (per-CU) carried 128 KB frag reads + 48 KB
// staging writes per K-tile (~2000 cyc @85 B/cyc) vs 1242 cyc MFMA -> LDS-
// bound. Fix: A-fragments come STRAIGHT FROM GLOBAL into registers (L1-
// resident 16 KB/tile, x4 wave duplication absorbed by L1), double-buffered
// one tile ahead. LDS carries only B: 64 KB reads + 32 KB writes (<1000 cyc).
// Per tile t: 8 ds_read_b128 (B frags, t) + 8 global_load_dwordx4 (A, t+1)
//             + 4 global_load_lds (B stage, t+2) + 32 MFMA + vmcnt(4) + barrier.
// vmcnt(4) at tile end leaves only B-stage(t+2)'s 4 loads in flight; drains
// A(t+1) regs and B(t+1) LDS. 3 LDS buffers x 32 KB = 96 KB.

#define VM4  asm volatile("s_waitcnt vmcnt(4)" ::: "memory")
#define VM0  asm volatile("s_waitcnt vmcnt(0)" ::: "memory")

#define STG4(buf, t) do {                           \
    const int ko_ = (t) * BK;                       \
    gload_lds16(sB0 + ko_, (buf) + lB0);            \
    gload_lds16(sB1 + ko_, (buf) + lB1);            \
    gload_lds16(sB2 + ko_, (buf) + lB2);            \
    gload_lds16(sB3 + ko_, (buf) + lB3);            \
} while (0)

// A fragments for tile t from GLOBAL: [0..3]=kk0 (i=0..3), [4..7]=kk1.
// aPi points at row (m0+wm*64+i*16+lr), k-offset kq*8 (ushort units).
#define LOADA(dst, t) do {                                   \
    dst[0] = *(const short8v*)(aP0 + (t) * 64);              \
    dst[1] = *(const short8v*)(aP1 + (t) * 64);              \
    dst[2] = *(const short8v*)(aP2 + (t) * 64);              \
    dst[3] = *(const short8v*)(aP3 + (t) * 64);              \
    dst[4] = *(const short8v*)(aP0 + (t) * 64 + 32);         \
    dst[5] = *(const short8v*)(aP1 + (t) * 64 + 32);         \
    dst[6] = *(const short8v*)(aP2 + (t) * 64 + 32);         \
    dst[7] = *(const short8v*)(aP3 + (t) * 64 + 32);         \
} while (0)

// B fragments from LDS buf: [0..3]=kk0 at swizzled chunk sc, [4..7]=kk1 at
// chunk c0^4 => per-thread byte delta so1 (+-64).
#define READB(bS, buf) do {                              \
    bS[0] = *(const short8v*)((buf) + rB0);              \
    bS[1] = *(const short8v*)((buf) + rB1);              \
    bS[2] = *(const short8v*)((buf) + rB2);              \
    bS[3] = *(const short8v*)((buf) + rB3);              \
    bS[4] = *(const short8v*)((buf) + rB0 + so1);        \
    bS[5] = *(const short8v*)((buf) + rB1 + so1);        \
    bS[6] = *(const short8v*)((buf) + rB2 + so1);        \
    bS[7] = *(const short8v*)((buf) + rB3 + so1);        \
} while (0)

#define MM1(aS, bS, ia, jb, i, j) \
    acc[i][j] = __builtin_amdgcn_mfma_f32_16x16x32_bf16(aS[ia], bS[jb], acc[i][j], 0, 0, 0)

#define MMALL(aS, bS) do {                                                           \
    MM1(aS,bS,0,0,0,0); MM1(aS,bS,0,1,0,1); MM1(aS,bS,0,2,0,2); MM1(aS,bS,0,3,0,3);  \
    MM1(aS,bS,1,0,1,0); MM1(aS,bS,1,1,1,1); MM1(aS,bS,1,2,1,2); MM1(aS,bS,1,3,1,3);  \
    MM1(aS,bS,2,0,2,0); MM1(aS,bS,2,1,2,1); MM1(aS,bS,2,2,2,2); MM1(aS,bS,2,3,2,3);  \
    MM1(aS,bS,3,0,3,0); MM1(aS,bS,3,1,3,1); MM1(aS,bS,3,2,3,2); MM1(aS,bS,3,3,3,3);  \
    MM1(aS,bS,4,4,0,0); MM1(aS,bS,4,5,0,1); MM1(aS,bS,4,6,0,2); MM1(aS,bS,4,7,0,3);  \
    MM1(aS,bS,5,4,1,0); MM1(aS,bS,5,5,1,1); MM1(aS,bS,5,6,1,2); MM1(aS,bS,5,7,1,3);  \
    MM1(aS,bS,6,4,2,0); MM1(aS,bS,6,5,2,1); MM1(aS,bS,6,6,2,2); MM1(aS,bS,6,7,2,3);  \
    MM1(aS,bS,7,4,3,0); MM1(aS,bS,7,5,3,1); MM1(aS,bS,7,6,3,2); MM1(aS,bS,7,7,3,3);  \
} while (0)

// Tile t: compute with aCur (loaded at t-1), load A(t+1) into aNxt,
// stage B(t+2), read B(t) this tile (compiler lgkm-waits feed the MFMAs).
#define ITER(bufRd, bufSt, tnext, aCur, aNxt) do {  \
    READB(bF, bufRd);                               \
    LOADA(aNxt, (tnext));                           \
    STG4(bufSt, (tnext) + 1);                       \
    __builtin_amdgcn_s_setprio(1);                  \
    MMALL(aCur, bF);                                \
    __builtin_amdgcn_s_setprio(0);                  \
    VM4;                                            \
    __builtin_amdgcn_s_barrier();                   \
} while (0)

__global__ __launch_bounds__(512, 2) void gemm_kernel(
        const unsigned short* __restrict__ Abf,   // [M][K]
        const unsigned short* __restrict__ Wt,    // [N][K]
        const float* __restrict__ bias,           // [N]
        float* __restrict__ C) {                  // [M][N]
    __shared__ __align__(128) char lds[3 * TILE_B];   // 96 KiB (B only)

    const int tid  = threadIdx.x;                 // 0..511
    const int lane = tid & 63;
    const int w    = tid >> 6;                    // 0..7
    const int wm   = w >> 2;                      // 0..1
    const int wn   = w & 3;                       // 0..3
    const int lr   = lane & 15;
    const int kq   = lane >> 4;                   // 0..3

    // XCD-chunked bijective block swizzle (256 blocks, 8 XCDs, 32/XCD)
    const int bid = blockIdx.x;
    const int wg  = (bid & 7) * 32 + (bid >> 3);
    const int m0  = (wg >> 4) * BM;               // 16 M-blocks
    const int n0  = (wg & 15) * BN;               // 16 N-blocks

    // ---- A fragment global base pointers (per-lane): row, k-offset kq*8
    const unsigned short* aP0 = Abf + (size_t)(m0 + wm * 64 +  0 + lr) * K_DIM + kq * 8;
    const unsigned short* aP1 = Abf + (size_t)(m0 + wm * 64 + 16 + lr) * K_DIM + kq * 8;
    const unsigned short* aP2 = Abf + (size_t)(m0 + wm * 64 + 32 + lr) * K_DIM + kq * 8;
    const unsigned short* aP3 = Abf + (size_t)(m0 + wm * 64 + 48 + lr) * K_DIM + kq * 8;

    // ---- B staging: slot p (16B): row = p>>3 (0..255), swz chunk (p&7)^(row&7)
    const int pB0 = tid,        pB1 = 512 + tid;
    const int pB2 = 1024 + tid, pB3 = 1536 + tid;
    const unsigned short* sB0 = Wt + (size_t)(n0 + (pB0 >> 3)) * K_DIM + 8 * ((pB0 & 7) ^ ((pB0 >> 3) & 7));
    const unsigned short* sB1 = Wt + (size_t)(n0 + (pB1 >> 3)) * K_DIM + 8 * ((pB1 & 7) ^ ((pB1 >> 3) & 7));
    const unsigned short* sB2 = Wt + (size_t)(n0 + (pB2 >> 3)) * K_DIM + 8 * ((pB2 & 7) ^ ((pB2 >> 3) & 7));
    const unsigned short* sB3 = Wt + (size_t)(n0 + (pB3 >> 3)) * K_DIM + 8 * ((pB3 & 7) ^ ((pB3 >> 3) & 7));
    const int lB0 = pB0 * 16, lB1 = pB1 * 16;
    const int lB2 = pB2 * 16, lB3 = pB3 * 16;

    // ---- B fragment read byte offsets; row&7 == lr&7.
    //      kk0 chunk c0 = kq^(lr&7); kk1 chunk = c0^4 => so1 = ((c0^4)-c0)*16.
    const int c0  = kq ^ (lr & 7);
    const int sc  = c0 * 16;
    const int so1 = ((c0 ^ 4) - c0) * 16;
    const int rB0 = (wn * 64 +  0 + lr) * 128 + sc;
    const int rB1 = (wn * 64 + 16 + lr) * 128 + sc;
    const int rB2 = (wn * 64 + 32 + lr) * 128 + sc;
    const int rB3 = (wn * 64 + 48 + lr) * 128 + sc;

    char* b0v = (char*)lds;
    char* b1v = (char*)lds + TILE_B;
    char* b2v = (char*)lds + 2 * TILE_B;

    f32x4 acc[4][4] = {};
    short8v aE[8], aO[8], bF[8];

    // ---- prologue: A(0)->aE first, then B stages 0,1.  VM4 leaves only
    //      B(1)'s 4 newest in flight; A(0) and B(0) landed.
    LOADA(aE, 0);
    STG4(b0v, 0);
    STG4(b1v, 1);
    VM4;
    __builtin_amdgcn_s_barrier();

    // ---- main loop: t = 0..59, period 6 (3 buffers x 2 reg parities) ----
    for (int tt = 0; tt < 10; ++tt) {
        const int t = tt * 6;
        ITER(b0v, b2v, t + 1, aE, aO);   // t+0: read B(t),   stage B(t+2)
        ITER(b1v, b0v, t + 2, aO, aE);   // t+1
        ITER(b2v, b1v, t + 3, aE, aO);   // t+2
        ITER(b0v, b2v, t + 4, aO, aE);   // t+3
        ITER(b1v, b0v, t + 5, aE, aO);   // t+4
        ITER(b2v, b1v, t + 6, aO, aE);   // t+5
    }
    // t=60: stage B(62); t=61: stage B(63)
    ITER(b0v, b2v, 61, aE, aO);
    ITER(b1v, b0v, 62, aO, aE);
    // t=62: read B(62) from b2, load A(63), no stage; VM0 drains everything.
    READB(bF, b2v);
    LOADA(aO, 63);
    __builtin_amdgcn_s_setprio(1);
    MMALL(aE, bF);
    __builtin_amdgcn_s_setprio(0);
    VM0;
    __builtin_amdgcn_s_barrier();
    // t=63: read B(63) from b0.
    READB(bF, b0v);
    __builtin_amdgcn_s_setprio(1);
    MMALL(aO, bF);
    __builtin_amdgcn_s_setprio(0);

    // ---- epilogue: C[m][n] = acc + bias[n] ----
    #pragma unroll
    for (int j = 0; j < 4; ++j) {
        const int n = n0 + wn * 64 + j * 16 + lr;
        const float bv = bias[n];
        #pragma unroll
        for (int i = 0; i < 4; ++i) {
            const int mb = m0 + wm * 64 + i * 16 + kq * 4;
            #pragma unroll
            for (int q = 0; q < 4; ++q)
                C[(size_t)(mb + q) * N_DIM + n] = acc[i][j][q] + bv;
        }
    }
}

extern "C" void kernel_launch(void* const* d_in, const int* in_sizes, int n_in,
                              void* d_out, int out_size, void* d_ws, size_t ws_size,
                              hipStream_t stream) {
    const float* inputs  = (const float*)d_in[0];   // (2048, 4096) f32
    const int*   indices = (const int*)  d_in[1];   // (4096, 4096) i32
    const float* mean    = (const float*)d_in[2];   // (4096,) f32
    const float* bias    = (const float*)d_in[3];   // (4096,) f32
    float* out = (float*)d_out;                     // (2048, 4096) f32

    unsigned short* Abf = (unsigned short*)d_ws;                                      // 16 MiB
    unsigned short* Wt  = (unsigned short*)((char*)d_ws + (size_t)M_DIM * K_DIM * 2); // 32 MiB

    convert_a_kernel<<<(M_DIM * K_DIM / 4) / 256, 256, 0, stream>>>(inputs, Abf);
    decode_transpose_kernel<<<dim3(N_DIM / 64, K_DIM / 64), 256, 0, stream>>>(indices, mean, Wt);
    gemm_kernel<<<256, 512, 0, stream>>>(Abf, Wt, bias, out);
}